// Round 6
// baseline (1389.269 us; speedup 1.0000x reference)
//
#include <hip/hip_runtime.h>
#include <hip/hip_bf16.h>

// ---------------------------------------------------------------------------
// RNNCell encoder: seq=512, batch=512, H=IN=300.
//   prep:   W_ih, W_hh -> bf16 zero-padded [320][320]; bias = b_ih+b_hh.
//   xproj:  R8 structure (kept): LDS staging, Bs triple-buffered, counted
//           vmcnt(3)/(2) + lgkm-only barrier; never a vmcnt(0) drain.
//   recur:  R11: half-K interval pipeline. Facts bank: latency-bound
//           (R9: 2x CUs + half LDS = 0 gain); chain interleave mandatory
//           (R10: solo 5-dep-chains -> MfmaUtil 4.5->3.1, 562->733us);
//           per-SIMD MFMA floor ~970 cy/step at 32 WG x 16 batch.
//           R11 splits each step at the k=160 boundary (h rows [0,160) ARE
//           the low-k operand half):
//             I1: read high-k frags of h(t-1); finish acc(t) (ks5-9, 3
//                 chains interleaved); tanh+write LOW tiles (n<160); barrier.
//             I2: read low-k frags of h(t); tanh+write HIGH tiles of acc(t)
//                 UNDER the read latency; seed acc(t+1)=x(t+1); low-k MFMAs
//                 (ks0-4); rotate x; barrier.
//           Disjoint read/write row-ranges per interval; single h buffer;
//           acc ping-pong via 2x-unrolled sets (static indexing). No h
//           zero-init needed (t=0 skips reads; writes cover all rows incl
//           pads before first use). Numerics = R10 order (passed).
// ---------------------------------------------------------------------------

typedef unsigned short u16;
typedef unsigned int   u32;
typedef __attribute__((ext_vector_type(8)))  short bf16x8;
typedef __attribute__((ext_vector_type(4)))  short s16x4;
typedef __attribute__((ext_vector_type(4)))  float f32x4;
typedef __attribute__((ext_vector_type(16))) float f32x16;
typedef __attribute__((ext_vector_type(2)))  unsigned int u32x2;
typedef __attribute__((ext_vector_type(4)))  unsigned int u32x4;

#define HID 300
#define KP  320
#define SEQ 512
#define BZ  512
#define MTOT (SEQ*BZ)

__device__ __forceinline__ u16 f2bf(float f) {
    u32 u = __float_as_uint(f);
    return (u16)((u + 0x7FFFu + ((u >> 16) & 1u)) >> 16);  // RNE
}
__device__ __forceinline__ float bf2f(u16 h) {
    return __uint_as_float((u32)h << 16);
}
__device__ __forceinline__ float tanh_fast(float x) {
    float e = __builtin_amdgcn_exp2f(x * 2.8853900817779268f);  // exp(2x)
    float r = __builtin_amdgcn_rcpf(e + 1.0f);
    return __builtin_fmaf(-2.0f, r, 1.0f);
}
__device__ __forceinline__ u32 pack2(float a, float b) {
    __hip_bfloat162 t = __float22bfloat162_rn(float2{a, b});  // v_cvt_pk_bf16_f32
    return *(u32*)&t;
}
// Workgroup barrier WITHOUT vmcnt drain: LDS ordering only.
__device__ __forceinline__ void lds_barrier() {
    asm volatile("s_waitcnt lgkmcnt(0)\n\ts_barrier" ::: "memory");
}

// ---------------------------------------------------------------------------
__global__ void prep_kernel(const float* __restrict__ wih,
                            const float* __restrict__ whh,
                            const float* __restrict__ bih,
                            const float* __restrict__ bhh,
                            u16* __restrict__ wihp, u16* __restrict__ whhp,
                            float* __restrict__ bias) {
    int n = blockIdx.x, k = threadIdx.x;
    bool v = (n < HID) && (k < HID);
    int src = n * HID + k, dst = n * KP + k;
    wihp[dst] = v ? f2bf(wih[src]) : (u16)0;
    whhp[dst] = v ? f2bf(whh[src]) : (u16)0;
    if (k == 0) bias[n] = (n < HID) ? (bih[n] + bhh[n]) : 0.0f;
}

// ---------------------------------------------------------------------------
// Phase 1 (R8): xp = in @ W_ih^T + bias. 2048 WGs x 512 thr.
// LDS: As[2] (A double-buf) + Bs[3] (B triple-buf, staged 2 ahead) = 76 KB.
__global__ __launch_bounds__(512, 1) void xproj_kernel(
    const float* __restrict__ in, const u16* __restrict__ wihp,
    const float* __restrict__ bias, u16* __restrict__ xp) {
    __shared__ __align__(16) u16 As[2][4096];
    __shared__ __align__(16) u16 Bs[3][10240];

    const int tid = threadIdx.x;
    const int w = tid >> 6, l = tid & 63;
    const int mi = w & 3, ni = w >> 2;
    const int l31 = l & 31, l5 = l >> 5;
    const int m0 = blockIdx.x * 128;

    const int sm = tid >> 2, skg = tid & 3;   // A staging: row, 8-k group

    f32x16 acc[5];
#pragma unroll
    for (int j = 0; j < 5; ++j)
#pragma unroll
        for (int r = 0; r < 16; ++r) acc[j][r] = 0.0f;

    const f32x4 zf = {0.f, 0.f, 0.f, 0.f};
    // Branchless A-load: always 2 VMEM ops (uniform vmcnt), clamp addr to
    // stay in-bounds, zero invalid k in registers.
    auto loadA = [&](int it, f32x4& v0, f32x4& v1) {
        int gk = it * 32 + skg * 8;
        int a0 = gk > 296 ? 296 : gk;
        int a1 = (gk + 4) > 296 ? 296 : (gk + 4);
        const float* p = in + (size_t)(m0 + sm) * HID;
        v0 = *(const f32x4*)(p + a0);
        v1 = *(const f32x4*)(p + a1);
        v0 = (gk > 296) ? zf : v0;        // gk>=304: fully padded
        v1 = ((gk + 4) > 296) ? zf : v1;  // k 300..303 -> 0
    };
    auto writeA = [&](int buf, const f32x4& v0, const f32x4& v1) {
        u32x4 pk;
        pk[0] = pack2(v0[0], v0[1]); pk[1] = pack2(v0[2], v0[3]);
        pk[2] = pack2(v1[0], v1[1]); pk[3] = pack2(v1[2], v1[3]);
        *(u32x4*)&As[buf][(skg >> 1) * 2048 + sm * 16 + (skg & 1) * 8] = pk;
    };
    auto stageB = [&](int buf, int it) {
#pragma unroll
        for (int s = 0; s < 3; ++s) {
            int i = w + 8 * s;                // wave-uniform predicate
            if (i < 20) {
                int c = i & 3, ng = i >> 2;
                int n = ng * 64 + l;
                const u16* g = wihp + n * KP + it * 32 + c * 8;
                u16* d = &Bs[buf][c * 2560 + ng * 512];
                __builtin_amdgcn_global_load_lds(
                    (const __attribute__((address_space(1))) void*)g,
                    (__attribute__((address_space(3))) void*)d, 16, 0, 0);
            }
        }
    };

    // Prologue: stage B for it=0 and it=1; A for it=0.
    {
        stageB(0, 0);
        f32x4 v0, v1;
        loadA(0, v0, v1);
        writeA(0, v0, v1);
        stageB(1, 1);
        asm volatile("s_waitcnt vmcnt(2)" ::: "memory");
        lds_barrier();
    }

    int cA = 0, cB = 0, sB = 2;
#pragma unroll 1
    for (int it = 0; it < 10; ++it) {
        f32x4 v0, v1;
        if (it < 9) loadA(it + 1, v0, v1);
        if (it < 8) stageB(sB, it + 2);
#pragma unroll
        for (int s = 0; s < 2; ++s) {
            bf16x8 a = *(const bf16x8*)&As[cA][s * 2048 + mi * 512 + l31 * 16 + l5 * 8];
#pragma unroll
            for (int j = 0; j < 5; ++j) {
                bf16x8 b = *(const bf16x8*)&Bs[cB][(s * 2 + l5) * 2560 + ((ni * 5 + j) * 32 + l31) * 8];
                acc[j] = __builtin_amdgcn_mfma_f32_32x32x16_bf16(a, b, acc[j], 0, 0, 0);
            }
        }
        if (it < 9) {
            writeA(cA ^ 1, v0, v1);
            if (it < 8) asm volatile("s_waitcnt vmcnt(3)" ::: "memory");
            else        asm volatile("s_waitcnt vmcnt(2)" ::: "memory");
            lds_barrier();
        }
        cA ^= 1;
        cB = (cB == 2) ? 0 : cB + 1;
        sB = (sB == 2) ? 0 : sB + 1;
    }

    const int mbase = m0 + mi * 32;
#pragma unroll
    for (int j = 0; j < 5; ++j) {
        int n = (ni * 5 + j) * 32 + l31;
        if (n < HID) {
            float bs = bias[n];
#pragma unroll
            for (int reg = 0; reg < 16; ++reg) {
                int row = (reg & 3) + 8 * (reg >> 2) + 4 * l5;
                xp[(size_t)(mbase + row) * HID + n] = f2bf(acc[j][reg] + bs);
            }
        }
    }
}

// ---------------------------------------------------------------------------
// Phase 2 (R11): recurrence. 32 WGs x 512 thr (8 waves, 2/SIMD), 16 batch/WG.
// Wave w owns tiles j0=w (LOW), j1=w+8 (LOW iff w<2 else HIGH),
// j2=w+16 (HIGH, w<4 only). Two intervals per step at the k=160 split.
__global__ __launch_bounds__(512, 2) void rnn_recur_kernel(
    const u16* __restrict__ xp, const u16* __restrict__ whhp,
    float* __restrict__ out) {
    __shared__ __align__(16) u16 hb[16 * 328];   // single-buffered h

    const int tid = threadIdx.x;
    const int w = tid >> 6;            // wave 0..7
    const int l = tid & 63;
    const int br = l & 15;             // batch-rel (B col / C col)
    const int q  = l >> 4;             // quad
    const int b0 = blockIdx.x * 16;
    const bool t3 = (w < 4);           // wave has tile j2
    const bool j1low = (w < 2);        // tile w+8 covers n in [128,160) -> LOW

    // W_hh A-fragments (load once; pinned to AGPRs)
    bf16x8 Af[3][10];
#pragma unroll
    for (int j = 0; j < 3; ++j) {
        if (j < 2 || t3) {
            const int nt = w + 8 * j;
            const u16* wrow = whhp + (size_t)(nt * 16 + br) * KP;
#pragma unroll
            for (int ks = 0; ks < 10; ++ks)
                Af[j][ks] = *(const bf16x8*)(wrow + ks * 32 + q * 8);
        }
    }
#pragma unroll
    for (int j = 0; j < 3; ++j)
        if (j < 2 || t3)
#pragma unroll
            for (int ks = 0; ks < 10; ++ks)
                asm volatile("" : "+a"(Af[j][ks]));

    // xp element offsets (step-invariant); -1 = fully-padded quad
    int xo[3];
#pragma unroll
    for (int j = 0; j < 3; ++j) {
        int n0 = (w + 8 * j) * 16 + q * 4;
        xo[j] = (n0 < HID && (j < 2 || t3)) ? ((b0 + br) * HID + n0) : -1;
    }

    const s16x4 z4 = {0, 0, 0, 0};
    s16x4 xc[3], xn[3];
#pragma unroll
    for (int j = 0; j < 3; ++j) {
        xc[j] = (xo[j] >= 0) ? *(const s16x4*)(xp + xo[j]) : z4;
        xn[j] = (xo[j] >= 0) ? *(const s16x4*)(xp + (size_t)BZ * HID + xo[j]) : z4;
    }

    // acc ping-pong sets. Prologue: acc(0) = x(0) (h(-1)=0 -> no MFMAs).
    f32x4 aP[3], aQ[3];
#pragma unroll
    for (int j = 0; j < 3; ++j)
#pragma unroll
        for (int r = 0; r < 4; ++r) {
            aP[j][r] = bf2f((u16)xc[j][r]);
            aQ[j][r] = 0.0f;
        }

    // one step = I1 + I2; aC = acc(t) (completed here), aN = acc(t+1) (started)
    auto stepf = [&](f32x4* aC, f32x4* aN, int t) {
        // ---- I1: finish acc(t) with high-k (ks5-9); tanh+write LOW tiles.
        if (t > 0) {
            bf16x8 bH[5];
#pragma unroll
            for (int ks = 0; ks < 5; ++ks)
                bH[ks] = *(const bf16x8*)&hb[br * 328 + (ks + 5) * 32 + q * 8];
#pragma unroll
            for (int ks = 0; ks < 5; ++ks) {
                aC[0] = __builtin_amdgcn_mfma_f32_16x16x32_bf16(Af[0][ks + 5], bH[ks], aC[0], 0, 0, 0);
                aC[1] = __builtin_amdgcn_mfma_f32_16x16x32_bf16(Af[1][ks + 5], bH[ks], aC[1], 0, 0, 0);
                if (t3)
                    aC[2] = __builtin_amdgcn_mfma_f32_16x16x32_bf16(Af[2][ks + 5], bH[ks], aC[2], 0, 0, 0);
            }
        }
        // tanh+write LOW tiles: j0 always; j1 when w<2 (rows n<160)
        {
            int n0 = w * 16 + q * 4;
            u32x2 pk;
            pk[0] = pack2(tanh_fast(aC[0][0]), tanh_fast(aC[0][1]));
            pk[1] = pack2(tanh_fast(aC[0][2]), tanh_fast(aC[0][3]));
            *(u32x2*)&hb[br * 328 + n0] = pk;
        }
        if (j1low) {
            int n0 = (w + 8) * 16 + q * 4;
            u32x2 pk;
            pk[0] = pack2(tanh_fast(aC[1][0]), tanh_fast(aC[1][1]));
            pk[1] = pack2(tanh_fast(aC[1][2]), tanh_fast(aC[1][3]));
            *(u32x2*)&hb[br * 328 + n0] = pk;
        }
        lds_barrier();

        // ---- I2: read low-k frags of h(t); tanh+write HIGH tiles of acc(t)
        //      under the read latency; start acc(t+1) = x(t+1) + W_low@h_low.
        bf16x8 bL[5];
#pragma unroll
        for (int ks = 0; ks < 5; ++ks)
            bL[ks] = *(const bf16x8*)&hb[br * 328 + ks * 32 + q * 8];

        // prefetch xp for t+2 (stays in flight across barriers)
        s16x4 xf[3];
        {
            int t2 = (t + 2 < SEQ) ? (t + 2) : (SEQ - 1);
            const u16* basef = xp + (size_t)t2 * (BZ * HID);
#pragma unroll
            for (int j = 0; j < 3; ++j)
                xf[j] = (xo[j] >= 0) ? *(const s16x4*)(basef + xo[j]) : z4;
        }

        // tanh+write HIGH tiles of acc(t): j1 when w>=2; j2 when w<4.
        // (independent of bL reads/MFMAs -> fills the LDS-latency window)
        if (!j1low) {
            int n0 = (w + 8) * 16 + q * 4;
            u32x2 pk;
            pk[0] = pack2(tanh_fast(aC[1][0]), tanh_fast(aC[1][1]));
            pk[1] = pack2(tanh_fast(aC[1][2]), tanh_fast(aC[1][3]));
            *(u32x2*)&hb[br * 328 + n0] = pk;
        }
        if (t3) {
            int n0 = (w + 16) * 16 + q * 4;
            u32x2 pk;
            pk[0] = pack2(tanh_fast(aC[2][0]), tanh_fast(aC[2][1]));
            pk[1] = pack2(tanh_fast(aC[2][2]), tanh_fast(aC[2][3]));
            *(u32x2*)&hb[br * 328 + n0] = pk;
        }

        // seed acc(t+1) with x(t+1); low-k MFMAs (ks0-4), 3 chains interleaved
#pragma unroll
        for (int j = 0; j < 3; ++j)
#pragma unroll
            for (int r = 0; r < 4; ++r)
                aN[j][r] = bf2f((u16)xn[j][r]);
#pragma unroll
        for (int ks = 0; ks < 5; ++ks) {
            aN[0] = __builtin_amdgcn_mfma_f32_16x16x32_bf16(Af[0][ks], bL[ks], aN[0], 0, 0, 0);
            aN[1] = __builtin_amdgcn_mfma_f32_16x16x32_bf16(Af[1][ks], bL[ks], aN[1], 0, 0, 0);
            if (t3)
                aN[2] = __builtin_amdgcn_mfma_f32_16x16x32_bf16(Af[2][ks], bL[ks], aN[2], 0, 0, 0);
        }

#pragma unroll
        for (int j = 0; j < 3; ++j) { xc[j] = xn[j]; xn[j] = xf[j]; }
        lds_barrier();
    };

#pragma unroll 1
    for (int t = 0; t < SEQ; t += 2) {
        stepf(aP, aQ, t);
        stepf(aQ, aP, t + 1);
    }

    // h(511) complete in hb (low written in I1(511), high in I2(511))
    for (int i = tid; i < 16 * HID; i += 512) {
        int r = i / HID, n = i - r * HID;
        out[(size_t)(b0 + r) * HID + n] = bf2f(hb[r * 328 + n]);
    }
}

// ---------------------------------------------------------------------------
extern "C" void kernel_launch(void* const* d_in, const int* in_sizes, int n_in,
                              void* d_out, int out_size, void* d_ws, size_t ws_size,
                              hipStream_t stream) {
    const float* in  = (const float*)d_in[0];
    const float* wih = (const float*)d_in[1];
    const float* whh = (const float*)d_in[2];
    const float* bih = (const float*)d_in[3];
    const float* bhh = (const float*)d_in[4];

    char* ws = (char*)d_ws;
    const size_t XP_BYTES = (size_t)MTOT * HID * sizeof(u16);   // 157,286,400
    u16*   xpb  = (u16*)ws;
    u16*   wihp = (u16*)(ws + XP_BYTES);
    u16*   whhp = (u16*)(ws + XP_BYTES + (size_t)KP * KP * 2);
    float* bias = (float*)(ws + XP_BYTES + 2 * (size_t)KP * KP * 2);

    prep_kernel<<<KP, KP, 0, stream>>>(wih, whh, bih, bhh, wihp, whhp, bias);
    xproj_kernel<<<MTOT / 128, 512, 0, stream>>>(in, wihp, bias, xpb);
    rnn_recur_kernel<<<BZ / 16, 512, 0, stream>>>(xpb, whhp, (float*)d_out);
}